// Round 1
// baseline (3150.625 us; speedup 1.0000x reference)
//
#include <hip/hip_runtime.h>

#define D 146
#define DP 148   // padded leading dim for float4-aligned W rows
#define NG 100
#define BN_EPS 1e-5f

// ---------------- GEMM: C[r][c] = rowscale[r] * sum_k A[r][k]*Wp[k][c] (+bias[c]) ----------------
// Wp is [146][148] zero-padded. Block = 320 threads: 8 row-groups x 37 col-groups(4 cols).
// 64 rows per block, 8 rows x 4 cols per thread.
__global__ __launch_bounds__(320) void gemm146(
    const float* __restrict__ A, const float* __restrict__ Wp,
    float* __restrict__ C, int nrows,
    const float* __restrict__ rowscale, const float* __restrict__ bias)
{
    int tid = threadIdx.x;
    int cg = tid % 37;
    int rg = tid / 37;
    if (rg >= 8) return;
    int r0 = blockIdx.x * 64 + rg * 8;
    int c = cg * 4;

    const float* Ap[8];
#pragma unroll
    for (int i = 0; i < 8; ++i) {
        int r = r0 + i;
        if (r > nrows - 1) r = nrows - 1;   // clamp (garbage rows never stored)
        Ap[i] = A + (size_t)r * D;
    }

    float acc[8][4] = {};
    const float* wp = Wp + c;
    for (int k = 0; k < D; ++k) {
        float4 w = *reinterpret_cast<const float4*>(wp + (size_t)k * DP);
#pragma unroll
        for (int i = 0; i < 8; ++i) {
            float a = Ap[i][k];
            acc[i][0] = fmaf(a, w.x, acc[i][0]);
            acc[i][1] = fmaf(a, w.y, acc[i][1]);
            acc[i][2] = fmaf(a, w.z, acc[i][2]);
            acc[i][3] = fmaf(a, w.w, acc[i][3]);
        }
    }

#pragma unroll
    for (int i = 0; i < 8; ++i) {
        int r = r0 + i;
        if (r >= nrows) break;
        float s = rowscale ? rowscale[r] : 1.0f;
#pragma unroll
        for (int j = 0; j < 4; ++j) {
            int cc = c + j;
            if (cc < D) {
                float v = acc[i][j] * s;
                if (bias) v += bias[cc];
                C[(size_t)r * D + cc] = v;
            }
        }
    }
}

// ---------------- pad weights into [5][146][148] ----------------
__global__ void padw_k(const float* __restrict__ Wemb, const float* __restrict__ Ws,
                       float* __restrict__ Wp)
{
    int idx = blockIdx.x * 256 + threadIdx.x;
    const int per = D * DP;
    if (idx >= 5 * per) return;
    int m = idx / per, rem = idx % per;
    int k = rem / DP, c = rem % DP;
    const float* Wsrc = (m == 0) ? Wemb : (Ws + (size_t)(m - 1) * D * D);
    Wp[idx] = (c < D) ? Wsrc[k * D + c] : 0.0f;
}

// ---------------- degree histograms ----------------
__global__ void deg_k(const int* __restrict__ src, const int* __restrict__ dst,
                      float* __restrict__ dso, float* __restrict__ dsi, int E)
{
    int e = blockIdx.x * 256 + threadIdx.x;
    if (e >= E) return;
    atomicAdd(&dso[src[e]], 1.0f);
    atomicAdd(&dsi[dst[e]], 1.0f);
}

__global__ void rsq_k(float* __restrict__ a, float* __restrict__ b, int N)
{
    int i = blockIdx.x * 256 + threadIdx.x;
    if (i >= N) return;
    a[i] = rsqrtf(fmaxf(a[i], 1.0f));
    b[i] = rsqrtf(fmaxf(b[i], 1.0f));
}

// ---------------- edge scatter-add: agg[dst] += hW[src] ----------------
__global__ void scatter_add_k(const float* __restrict__ hW, const int* __restrict__ src,
                              const int* __restrict__ dst, float* __restrict__ agg,
                              long long total)
{
    long long idx = (long long)blockIdx.x * 256 + threadIdx.x;
    if (idx >= total) return;
    int e = (int)(idx / D);
    int c = (int)(idx % D);
    int s = src[e], t = dst[e];
    atomicAdd(&agg[(size_t)t * D + c], hW[(size_t)s * D + c]);
}

// ---------------- h_pre = (agg * norm_dst + b) * snorm ----------------
__global__ void p1_k(const float* __restrict__ agg, const float* __restrict__ nd,
                     const float* __restrict__ sn, const float* __restrict__ b,
                     float* __restrict__ hpre, long long total)
{
    long long idx = (long long)blockIdx.x * 256 + threadIdx.x;
    if (idx >= total) return;
    int r = (int)(idx / D);
    int c = (int)(idx % D);
    hpre[idx] = (agg[idx] * nd[r] + b[c]) * sn[r];
}

// ---------------- column sums for BN (thread = column, coalesced) ----------------
__global__ __launch_bounds__(256) void colsum_k(const float* __restrict__ hpre,
                                                float* __restrict__ stats, int N, int chunk)
{
    int c = threadIdx.x;
    if (c >= D) return;
    int r0 = blockIdx.x * chunk;
    int r1 = min(N, r0 + chunk);
    float s = 0.0f, q = 0.0f;
    for (int r = r0; r < r1; ++r) {
        float v = hpre[(size_t)r * D + c];
        s += v;
        q = fmaf(v, v, q);
    }
    atomicAdd(&stats[c], s);
    atomicAdd(&stats[D + c], q);
}

__global__ void bnfin_k(float* __restrict__ stats, int N)
{
    int c = threadIdx.x;
    if (c >= D) return;
    float mean = stats[c] / (float)N;
    float var = stats[D + c] / (float)N - mean * mean;
    if (var < 0.0f) var = 0.0f;
    stats[2 * D + c] = mean;
    stats[3 * D + c] = rsqrtf(var + BN_EPS);
}

// ---------------- h = h + relu(bn(hpre)) ----------------
__global__ void p2_k(float* __restrict__ h, const float* __restrict__ hpre,
                     const float* __restrict__ stats, const float* __restrict__ gamma,
                     const float* __restrict__ beta, long long total)
{
    long long idx = (long long)blockIdx.x * 256 + threadIdx.x;
    if (idx >= total) return;
    int c = (int)(idx % D);
    float v = (hpre[idx] - stats[2 * D + c]) * stats[3 * D + c] * gamma[c] + beta[c];
    h[idx] += fmaxf(v, 0.0f);
}

// ---------------- hg[g] += sum_i h[i]*snorm[i]^2 (mean-nodes; graph_ids sorted) ----------------
__global__ __launch_bounds__(256) void hg_k(const float* __restrict__ h, const float* __restrict__ sn,
                                            const int* __restrict__ gid, float* __restrict__ hg,
                                            int N, int chunk)
{
    int c = threadIdx.x;
    if (c >= D) return;
    int r0 = blockIdx.x * chunk;
    int r1 = min(N, r0 + chunk);
    if (r0 >= r1) return;
    int g = gid[r0];
    float acc = 0.0f;
    for (int r = r0; r < r1; ++r) {
        int gr = gid[r];
        if (gr != g) {
            atomicAdd(&hg[(size_t)g * D + c], acc);
            acc = 0.0f;
            g = gr;
        }
        float w = sn[r];
        acc = fmaf(h[(size_t)r * D + c], w * w, acc);
    }
    atomicAdd(&hg[(size_t)g * D + c], acc);
}

// ---------------- small dense layer (readout) ----------------
__global__ void sgemm_k(const float* __restrict__ A, const float* __restrict__ W,
                        const float* __restrict__ b, float* __restrict__ Cc,
                        int M, int K, int Nc, int dorelu)
{
    int idx = blockIdx.x * 256 + threadIdx.x;
    if (idx >= M * Nc) return;
    int m = idx / Nc, n = idx % Nc;
    float s = b[n];
    for (int k = 0; k < K; ++k) s = fmaf(A[(size_t)m * K + k], W[(size_t)k * Nc + n], s);
    Cc[idx] = dorelu ? fmaxf(s, 0.0f) : s;
}

extern "C" void kernel_launch(void* const* d_in, const int* in_sizes, int n_in,
                              void* d_out, int out_size, void* d_ws, size_t ws_size,
                              hipStream_t stream)
{
    const float* nodes  = (const float*)d_in[0];
    const float* snorm  = (const float*)d_in[1];
    const float* Wemb   = (const float*)d_in[2];
    const float* bemb   = (const float*)d_in[3];
    const float* Ws     = (const float*)d_in[4];
    const float* bs     = (const float*)d_in[5];
    const float* gammas = (const float*)d_in[6];
    const float* betas  = (const float*)d_in[7];
    const float* Wr0    = (const float*)d_in[8];
    const float* br0    = (const float*)d_in[9];
    const float* Wr1    = (const float*)d_in[10];
    const float* br1    = (const float*)d_in[11];
    const float* Wr2    = (const float*)d_in[12];
    const float* br2    = (const float*)d_in[13];
    const int*   src    = (const int*)d_in[14];
    const int*   dst    = (const int*)d_in[15];
    const int*   gid    = (const int*)d_in[16];

    int N = in_sizes[0] / D;
    int E = in_sizes[14];

    float* ws = (float*)d_ws;
    size_t off = 0;
    float* Wp    = ws + off; off += (size_t)5 * D * DP;
    float* nsrc  = ws + off; off += N;
    float* ndst  = ws + off; off += N;
    float* h     = ws + off; off += (size_t)N * D;
    float* hW    = ws + off; off += (size_t)N * D;   // reused as h_pre
    float* agg   = ws + off; off += (size_t)N * D;
    float* stats = ws + off; off += 4 * D;
    float* hg    = ws + off; off += (size_t)NG * D;
    float* z1    = ws + off; off += (size_t)NG * 73;
    float* z2    = ws + off; off += (size_t)NG * 36;

    long long ntot = (long long)N * D;
    long long etot = (long long)E * D;

    // init
    hipMemsetAsync(nsrc, 0, 2 * (size_t)N * sizeof(float), stream);       // nsrc+ndst contiguous
    hipMemsetAsync(hg, 0, (size_t)NG * D * sizeof(float), stream);
    padw_k<<<(5 * D * DP + 255) / 256, 256, 0, stream>>>(Wemb, Ws, Wp);
    deg_k<<<(E + 255) / 256, 256, 0, stream>>>(src, dst, nsrc, ndst, E);
    rsq_k<<<(N + 255) / 256, 256, 0, stream>>>(nsrc, ndst, N);

    // embedding
    gemm146<<<(N + 63) / 64, 320, 0, stream>>>(nodes, Wp, h, N, nullptr, bemb);

    for (int l = 0; l < 4; ++l) {
        hipMemsetAsync(agg, 0, (size_t)N * D * sizeof(float), stream);
        hipMemsetAsync(stats, 0, 2 * D * sizeof(float), stream);
        // hW = (h * norm_src) @ W   (row scale folded into output)
        gemm146<<<(N + 63) / 64, 320, 0, stream>>>(h, Wp + (size_t)(l + 1) * D * DP, hW, N, nsrc, nullptr);
        scatter_add_k<<<(int)((etot + 255) / 256), 256, 0, stream>>>(hW, src, dst, agg, etot);
        p1_k<<<(int)((ntot + 255) / 256), 256, 0, stream>>>(agg, ndst, snorm, bs + (size_t)l * D, hW, ntot);
        colsum_k<<<100, 256, 0, stream>>>(hW, stats, N, (N + 99) / 100);
        bnfin_k<<<1, 256, 0, stream>>>(stats, N);
        p2_k<<<(int)((ntot + 255) / 256), 256, 0, stream>>>(h, hW, stats, gammas + (size_t)l * D, betas + (size_t)l * D, ntot);
        hg_k<<<(N + 511) / 512, 256, 0, stream>>>(h, snorm, gid, hg, N, 512);
    }

    // readout MLP: 146 -> 73 -> 36 -> 10
    sgemm_k<<<(NG * 73 + 255) / 256, 256, 0, stream>>>(hg, Wr0, br0, z1, NG, D, 73, 1);
    sgemm_k<<<(NG * 36 + 255) / 256, 256, 0, stream>>>(z1, Wr1, br1, z2, NG, 73, 36, 1);
    sgemm_k<<<(NG * 10 + 255) / 256, 256, 0, stream>>>(z2, Wr2, br2, (float*)d_out, NG, 36, 10, 0);
}

// Round 2
// 1064.868 us; speedup vs baseline: 2.9587x; 2.9587x over previous
//
#include <hip/hip_runtime.h>

#define D 146
#define DP 160      // padded W leading dim (float4 groups, 40 per row)
#define SROW 147    // LDS A-tile stride (<=2-way bank aliasing for 8 row-groups)
#define NG 100
#define BN_EPS 1e-5f

// ---------------- GEMM: C[r][c] = rowscale[r] * (A[r] @ Wp)[c] (+bias[c]) ----------------
// Wp is [146][160] zero-padded. Block = 320 threads: 8 row-groups x 40 col-groups(4 cols).
// A tile 64x146 staged in LDS.
__global__ __launch_bounds__(320) void gemm146(
    const float* __restrict__ A, const float* __restrict__ Wp,
    float* __restrict__ C, int nrows,
    const float* __restrict__ rowscale, const float* __restrict__ bias)
{
    __shared__ float As[64 * SROW];
    int tid = threadIdx.x;
    int row0 = blockIdx.x * 64;

    // stage A tile (contiguous 64*146 floats) via float4, clamped at the end
    {
        const float4* A4 = reinterpret_cast<const float4*>(A);
        int base4 = blockIdx.x * (64 * D / 4);       // 2336 per block
        int limit4 = nrows * D / 4 - 1;              // N*D divisible by 4
        for (int i = tid; i < 64 * D / 4; i += 320) {
            float4 v = A4[min(base4 + i, limit4)];
            int f = i * 4;
            int r = f / D, c = f - r * D;
#pragma unroll
            for (int j = 0; j < 4; ++j) {
                int cc = c + j, rr = r;
                if (cc >= D) { cc -= D; rr += 1; }
                As[rr * SROW + cc] = (&v.x)[j];
            }
        }
    }
    __syncthreads();

    int cg = tid % 40;
    int rg = tid / 40;
    int c = cg * 4;
    const float4* W4 = reinterpret_cast<const float4*>(Wp);

    float acc[8][4] = {};
    for (int k = 0; k < D; k += 2) {
        float4 w0 = W4[k * (DP / 4) + cg];
        float4 w1 = W4[(k + 1) * (DP / 4) + cg];
#pragma unroll
        for (int i = 0; i < 8; ++i) {
            int base = (rg * 8 + i) * SROW + k;
            float a0 = As[base];
            float a1 = As[base + 1];
            acc[i][0] = fmaf(a0, w0.x, acc[i][0]);
            acc[i][1] = fmaf(a0, w0.y, acc[i][1]);
            acc[i][2] = fmaf(a0, w0.z, acc[i][2]);
            acc[i][3] = fmaf(a0, w0.w, acc[i][3]);
            acc[i][0] = fmaf(a1, w1.x, acc[i][0]);
            acc[i][1] = fmaf(a1, w1.y, acc[i][1]);
            acc[i][2] = fmaf(a1, w1.z, acc[i][2]);
            acc[i][3] = fmaf(a1, w1.w, acc[i][3]);
        }
    }

#pragma unroll
    for (int i = 0; i < 8; ++i) {
        int r = row0 + rg * 8 + i;
        if (r >= nrows) continue;
        float s = rowscale ? rowscale[r] : 1.0f;
#pragma unroll
        for (int j = 0; j < 4; ++j) {
            int cc = c + j;
            if (cc < D) {
                float v = acc[i][j] * s;
                if (bias) v += bias[cc];
                C[(size_t)r * D + cc] = v;
            }
        }
    }
}

// ---------------- pad weights into [5][146][160] ----------------
__global__ void padw_k(const float* __restrict__ Wemb, const float* __restrict__ Ws,
                       float* __restrict__ Wp)
{
    int idx = blockIdx.x * 256 + threadIdx.x;
    const int per = D * DP;
    if (idx >= 5 * per) return;
    int m = idx / per, rem = idx % per;
    int k = rem / DP, c = rem % DP;
    const float* Wsrc = (m == 0) ? Wemb : (Ws + (size_t)(m - 1) * D * D);
    Wp[idx] = (c < D) ? Wsrc[k * D + c] : 0.0f;
}

// ---------------- degree histograms (int) ----------------
__global__ void deg_k(const int* __restrict__ src, const int* __restrict__ dst,
                      int* __restrict__ co, int* __restrict__ ci, int E)
{
    int e = blockIdx.x * 256 + threadIdx.x;
    if (e >= E) return;
    atomicAdd(&co[src[e]], 1);
    atomicAdd(&ci[dst[e]], 1);
}

__global__ void rsq_k(const int* __restrict__ co, const int* __restrict__ ci,
                      float* __restrict__ ns, float* __restrict__ nd, int N)
{
    int i = blockIdx.x * 256 + threadIdx.x;
    if (i >= N) return;
    ns[i] = rsqrtf(fmaxf((float)co[i], 1.0f));
    nd[i] = rsqrtf(fmaxf((float)ci[i], 1.0f));
}

// ---------------- exclusive scan of in-degrees -> rowptr + cursor ----------------
__global__ __launch_bounds__(1024) void scan_k(const int* __restrict__ cnt,
                                               int* __restrict__ rowptr,
                                               int* __restrict__ cursor, int N, int E)
{
    __shared__ int lds[1024];
    int t = threadIdx.x;
    int chunk = (N + 1023) >> 10;
    int lo = t * chunk, hi = min(N, lo + chunk);
    int s = 0;
    for (int i = lo; i < hi; ++i) s += cnt[i];
    lds[t] = s;
    __syncthreads();
    for (int off = 1; off < 1024; off <<= 1) {
        int v = lds[t];
        int u = (t >= off) ? lds[t - off] : 0;
        __syncthreads();
        lds[t] = v + u;
        __syncthreads();
    }
    int base = (t > 0) ? lds[t - 1] : 0;
    for (int i = lo; i < hi; ++i) { rowptr[i] = base; cursor[i] = base; base += cnt[i]; }
    if (t == 0) rowptr[N] = E;
}

// ---------------- CSR fill: esrc[slot(dst)] = src ----------------
__global__ void csrfill_k(const int* __restrict__ src, const int* __restrict__ dst,
                          int* __restrict__ cursor, int* __restrict__ esrc, int E)
{
    int e = blockIdx.x * 256 + threadIdx.x;
    if (e >= E) return;
    int pos = atomicAdd(&cursor[dst[e]], 1);
    esrc[pos] = src[e];
}

// ---------------- CSR gather-sum + p1 epilogue + BN column stats ----------------
// block = 4 waves; each wave a contiguous node sub-chunk; lane owns cols {l, l+64, l+128}
__global__ __launch_bounds__(256) void agg_k(
    const float* __restrict__ hW, const int* __restrict__ esrc,
    const int* __restrict__ rowptr, const float* __restrict__ nd,
    const float* __restrict__ sn, const float* __restrict__ bias,
    float* __restrict__ hpre, float* __restrict__ stats, int N)
{
    __shared__ float rs[4][D];
    __shared__ float rq[4][D];
    int lane = threadIdx.x & 63;
    int wave = threadIdx.x >> 6;
    int per = (N + gridDim.x - 1) / gridDim.x;
    int n0 = blockIdx.x * per;
    int n1 = min(N, n0 + per);
    int wper = (per + 3) >> 2;
    int w0 = min(n1, n0 + wave * wper);
    int w1 = min(n1, w0 + wper);

    int c0 = lane, c1 = lane + 64, c2 = lane + 128;
    bool v2 = (c2 < D);
    int c2m = v2 ? c2 : 0;
    float bias0 = bias[c0], bias1 = bias[c1], bias2 = bias[c2m];
    float s0 = 0, s1 = 0, s2 = 0, q0 = 0, q1 = 0, q2 = 0;

    for (int n = w0; n < w1; ++n) {
        int e = rowptr[n], eend = rowptr[n + 1];
        float a0 = 0, a1 = 0, a2 = 0, b0 = 0, b1 = 0, b2 = 0;
        for (; e + 1 < eend; e += 2) {
            const float* ra = hW + (size_t)esrc[e] * D;
            const float* rb = hW + (size_t)esrc[e + 1] * D;
            a0 += ra[c0]; b0 += rb[c0];
            a1 += ra[c1]; b1 += rb[c1];
            if (v2) { a2 += ra[c2]; b2 += rb[c2]; }
        }
        if (e < eend) {
            const float* ra = hW + (size_t)esrc[e] * D;
            a0 += ra[c0]; a1 += ra[c1]; if (v2) a2 += ra[c2];
        }
        a0 += b0; a1 += b1; a2 += b2;
        float ndv = nd[n], snv = sn[n];
        float h0 = (a0 * ndv + bias0) * snv;
        float h1 = (a1 * ndv + bias1) * snv;
        float h2 = v2 ? (a2 * ndv + bias2) * snv : 0.0f;
        size_t rbse = (size_t)n * D;
        hpre[rbse + c0] = h0;
        hpre[rbse + c1] = h1;
        if (v2) hpre[rbse + c2] = h2;
        s0 += h0; q0 = fmaf(h0, h0, q0);
        s1 += h1; q1 = fmaf(h1, h1, q1);
        s2 += h2; q2 = fmaf(h2, h2, q2);
    }
    rs[wave][c0] = s0; rq[wave][c0] = q0;
    rs[wave][c1] = s1; rq[wave][c1] = q1;
    if (v2) { rs[wave][c2] = s2; rq[wave][c2] = q2; }
    __syncthreads();
    for (int cc = threadIdx.x; cc < D; cc += 256) {
        float ss = rs[0][cc] + rs[1][cc] + rs[2][cc] + rs[3][cc];
        float qq = rq[0][cc] + rq[1][cc] + rq[2][cc] + rq[3][cc];
        atomicAdd(&stats[cc], ss);
        atomicAdd(&stats[D + cc], qq);
    }
}

__global__ void bnfin_k(float* __restrict__ stats, int N)
{
    int c = threadIdx.x;
    if (c >= D) return;
    float mean = stats[c] / (float)N;
    float var = stats[D + c] / (float)N - mean * mean;
    if (var < 0.0f) var = 0.0f;
    stats[2 * D + c] = mean;
    stats[3 * D + c] = rsqrtf(var + BN_EPS);
}

// ---------------- h += relu(bn(hpre)); hg[g] += h*sn^2 (gid sorted, fused) ----------------
__global__ __launch_bounds__(256) void p2hg_k(
    float* __restrict__ h, const float* __restrict__ hpre,
    const float* __restrict__ stats, const float* __restrict__ gamma,
    const float* __restrict__ beta, const float* __restrict__ sn,
    const int* __restrict__ gid, float* __restrict__ hg, int N)
{
    int lane = threadIdx.x & 63;
    int wave = threadIdx.x >> 6;
    int per = (N + gridDim.x - 1) / gridDim.x;
    int n0 = blockIdx.x * per;
    int n1 = min(N, n0 + per);
    int wper = (per + 3) >> 2;
    int w0 = min(n1, n0 + wave * wper);
    int w1 = min(n1, w0 + wper);
    if (w0 >= w1) return;

    int c0 = lane, c1 = lane + 64, c2 = lane + 128;
    bool v2 = (c2 < D);
    int c2m = v2 ? c2 : 0;
    float m0 = stats[2 * D + c0], r0 = stats[3 * D + c0], g0 = gamma[c0], t0 = beta[c0];
    float m1 = stats[2 * D + c1], r1 = stats[3 * D + c1], g1 = gamma[c1], t1 = beta[c1];
    float m2 = stats[2 * D + c2m], r2 = stats[3 * D + c2m], g2 = gamma[c2m], t2 = beta[c2m];

    int g = gid[w0];
    float a0 = 0, a1 = 0, a2 = 0;
    for (int n = w0; n < w1; ++n) {
        int gr = gid[n];
        if (gr != g) {
            atomicAdd(&hg[(size_t)g * D + c0], a0);
            atomicAdd(&hg[(size_t)g * D + c1], a1);
            if (v2) atomicAdd(&hg[(size_t)g * D + c2], a2);
            a0 = a1 = a2 = 0;
            g = gr;
        }
        size_t rb = (size_t)n * D;
        float w2 = sn[n]; w2 *= w2;
        float x0 = h[rb + c0] + fmaxf((hpre[rb + c0] - m0) * r0 * g0 + t0, 0.0f);
        float x1 = h[rb + c1] + fmaxf((hpre[rb + c1] - m1) * r1 * g1 + t1, 0.0f);
        h[rb + c0] = x0; a0 = fmaf(x0, w2, a0);
        h[rb + c1] = x1; a1 = fmaf(x1, w2, a1);
        if (v2) {
            float x2 = h[rb + c2] + fmaxf((hpre[rb + c2] - m2) * r2 * g2 + t2, 0.0f);
            h[rb + c2] = x2; a2 = fmaf(x2, w2, a2);
        }
    }
    atomicAdd(&hg[(size_t)g * D + c0], a0);
    atomicAdd(&hg[(size_t)g * D + c1], a1);
    if (v2) atomicAdd(&hg[(size_t)g * D + c2], a2);
}

// ---------------- small dense layer (readout) ----------------
__global__ void sgemm_k(const float* __restrict__ A, const float* __restrict__ W,
                        const float* __restrict__ b, float* __restrict__ Cc,
                        int M, int K, int Nc, int dorelu)
{
    int idx = blockIdx.x * 256 + threadIdx.x;
    if (idx >= M * Nc) return;
    int m = idx / Nc, n = idx % Nc;
    float s = b[n];
    for (int k = 0; k < K; ++k) s = fmaf(A[(size_t)m * K + k], W[(size_t)k * Nc + n], s);
    Cc[idx] = dorelu ? fmaxf(s, 0.0f) : s;
}

extern "C" void kernel_launch(void* const* d_in, const int* in_sizes, int n_in,
                              void* d_out, int out_size, void* d_ws, size_t ws_size,
                              hipStream_t stream)
{
    const float* nodes  = (const float*)d_in[0];
    const float* snorm  = (const float*)d_in[1];
    const float* Wemb   = (const float*)d_in[2];
    const float* bemb   = (const float*)d_in[3];
    const float* Ws     = (const float*)d_in[4];
    const float* bs     = (const float*)d_in[5];
    const float* gammas = (const float*)d_in[6];
    const float* betas  = (const float*)d_in[7];
    const float* Wr0    = (const float*)d_in[8];
    const float* br0    = (const float*)d_in[9];
    const float* Wr1    = (const float*)d_in[10];
    const float* br1    = (const float*)d_in[11];
    const float* Wr2    = (const float*)d_in[12];
    const float* br2    = (const float*)d_in[13];
    const int*   src    = (const int*)d_in[14];
    const int*   dst    = (const int*)d_in[15];
    const int*   gid    = (const int*)d_in[16];

    int N = in_sizes[0] / D;
    int E = in_sizes[14];

    float* ws = (float*)d_ws;
    size_t off = 0;
    float* Wp    = ws + off; off += (size_t)5 * D * DP;
    float* nsrc  = ws + off; off += N;
    float* ndst  = ws + off; off += N;
    float* h     = ws + off; off += (size_t)N * D;
    float* hW    = ws + off; off += (size_t)N * D;
    float* hpre  = ws + off; off += (size_t)N * D;
    float* stats = ws + off; off += 4 * D;
    float* hg    = ws + off; off += (size_t)NG * D;
    float* z1    = ws + off; off += (size_t)NG * 73;
    float* z2    = ws + off; off += (size_t)NG * 36;
    int* cnt_out = (int*)(ws + off); off += N;
    int* cnt_in  = (int*)(ws + off); off += N;
    int* rowptr  = (int*)(ws + off); off += N + 4;
    int* cursor  = (int*)(ws + off); off += N;
    int* esrc    = (int*)(ws + off); off += E;

    // setup: degrees, norms, CSR
    hipMemsetAsync(cnt_out, 0, 2 * (size_t)N * sizeof(int), stream);
    hipMemsetAsync(hg, 0, (size_t)NG * D * sizeof(float), stream);
    padw_k<<<(5 * D * DP + 255) / 256, 256, 0, stream>>>(Wemb, Ws, Wp);
    deg_k<<<(E + 255) / 256, 256, 0, stream>>>(src, dst, cnt_out, cnt_in, E);
    rsq_k<<<(N + 255) / 256, 256, 0, stream>>>(cnt_out, cnt_in, nsrc, ndst, N);
    scan_k<<<1, 1024, 0, stream>>>(cnt_in, rowptr, cursor, N, E);
    csrfill_k<<<(E + 255) / 256, 256, 0, stream>>>(src, dst, cursor, esrc, E);

    // embedding
    gemm146<<<(N + 63) / 64, 320, 0, stream>>>(nodes, Wp, h, N, nullptr, bemb);

    for (int l = 0; l < 4; ++l) {
        hipMemsetAsync(stats, 0, 2 * D * sizeof(float), stream);
        gemm146<<<(N + 63) / 64, 320, 0, stream>>>(h, Wp + (size_t)(l + 1) * D * DP, hW, N, nsrc, nullptr);
        agg_k<<<1024, 256, 0, stream>>>(hW, esrc, rowptr, ndst, snorm, bs + (size_t)l * D, hpre, stats, N);
        bnfin_k<<<1, 256, 0, stream>>>(stats, N);
        p2hg_k<<<512, 256, 0, stream>>>(h, hpre, stats, gammas + (size_t)l * D, betas + (size_t)l * D,
                                        snorm, gid, hg, N);
    }

    // readout MLP: 146 -> 73 -> 36 -> 10
    sgemm_k<<<(NG * 73 + 255) / 256, 256, 0, stream>>>(hg, Wr0, br0, z1, NG, D, 73, 1);
    sgemm_k<<<(NG * 36 + 255) / 256, 256, 0, stream>>>(z1, Wr1, br1, z2, NG, 73, 36, 1);
    sgemm_k<<<(NG * 10 + 255) / 256, 256, 0, stream>>>(z2, Wr2, br2, (float*)d_out, NG, 36, 10, 0);
}

// Round 3
// 887.754 us; speedup vs baseline: 3.5490x; 1.1995x over previous
//
#include <hip/hip_runtime.h>
#include <hip/hip_fp16.h>

#define D 146
#define DP 160      // padded W leading dim in floats (40 float4 per row)
#define AS 152      // padded fp16 activation row (19 uint4 per row)
#define NG 100
#define BN_EPS 1e-5f

// ---------------- pad weights into [5][146][160] fp32 ----------------
__global__ void padw_k(const float* __restrict__ Wemb, const float* __restrict__ Ws,
                       float* __restrict__ Wp)
{
    int idx = blockIdx.x * 256 + threadIdx.x;
    const int per = D * DP;
    if (idx >= 5 * per) return;
    int m = idx / per, rem = idx % per;
    int k = rem / DP, c = rem % DP;
    const float* Wsrc = (m == 0) ? Wemb : (Ws + (size_t)(m - 1) * D * D);
    Wp[idx] = (c < D) ? Wsrc[k * D + c] : 0.0f;
}

// ---------------- nodes fp32 [N][146] -> fp16 [N][152] ----------------
__global__ void cvtnodes_k(const float* __restrict__ nodes, __half2* __restrict__ out2, int N)
{
    int idx = blockIdx.x * 256 + threadIdx.x;
    if (idx >= N * (AS / 2)) return;
    int r = idx / (AS / 2), j = idx % (AS / 2);
    int c = 2 * j;
    float v0 = (c < D) ? nodes[(size_t)r * D + c] : 0.0f;
    float v1 = (c + 1 < D) ? nodes[(size_t)r * D + c + 1] : 0.0f;
    out2[idx] = __floats2half2_rn(v0, v1);
}

// ---------------- degree histograms ----------------
__global__ void deg_k(const int* __restrict__ src, const int* __restrict__ dst,
                      int* __restrict__ co, int* __restrict__ ci, int E)
{
    int e = blockIdx.x * 256 + threadIdx.x;
    if (e >= E) return;
    atomicAdd(&co[src[e]], 1);
    atomicAdd(&ci[dst[e]], 1);
}

__global__ void rsq_k(const int* __restrict__ co, const int* __restrict__ ci,
                      float* __restrict__ ns, float* __restrict__ nd, int N)
{
    int i = blockIdx.x * 256 + threadIdx.x;
    if (i >= N) return;
    ns[i] = rsqrtf(fmaxf((float)co[i], 1.0f));
    nd[i] = rsqrtf(fmaxf((float)ci[i], 1.0f));
}

// ---------------- parallel exclusive scan (3 phases) ----------------
__global__ __launch_bounds__(256) void pscan1_k(const int* __restrict__ cnt,
                                                int* __restrict__ bsum, int N)
{
    __shared__ int lds[256];
    int t = blockIdx.x * 256 + threadIdx.x;
    lds[threadIdx.x] = (t < N) ? cnt[t] : 0;
    __syncthreads();
    for (int s = 128; s > 0; s >>= 1) {
        if (threadIdx.x < s) lds[threadIdx.x] += lds[threadIdx.x + s];
        __syncthreads();
    }
    if (threadIdx.x == 0) bsum[blockIdx.x] = lds[0];
}

__global__ __launch_bounds__(256) void pscan2_k(const int* __restrict__ bsum,
                                                int* __restrict__ boff, int nb)
{
    __shared__ int lds[256];
    int t = threadIdx.x;
    int v = (t < nb) ? bsum[t] : 0;
    lds[t] = v;
    __syncthreads();
    for (int off = 1; off < 256; off <<= 1) {
        int u = (t >= off) ? lds[t - off] : 0;
        __syncthreads();
        lds[t] += u;
        __syncthreads();
    }
    boff[t] = lds[t] - v;
}

__global__ __launch_bounds__(256) void pscan3_k(const int* __restrict__ cnt,
                                                const int* __restrict__ boff,
                                                int* __restrict__ rowptr,
                                                int* __restrict__ cursor, int N, int E)
{
    __shared__ int lds[256];
    int t = blockIdx.x * 256 + threadIdx.x;
    int v = (t < N) ? cnt[t] : 0;
    lds[threadIdx.x] = v;
    __syncthreads();
    for (int off = 1; off < 256; off <<= 1) {
        int u = (threadIdx.x >= off) ? lds[threadIdx.x - off] : 0;
        __syncthreads();
        lds[threadIdx.x] += u;
        __syncthreads();
    }
    if (t < N) {
        int r = boff[blockIdx.x] + lds[threadIdx.x] - v;
        rowptr[t] = r;
        cursor[t] = r;
    }
    if (t == 0) rowptr[N] = E;
}

// ---------------- CSR fill ----------------
__global__ void csrfill_k(const int* __restrict__ src, const int* __restrict__ dst,
                          int* __restrict__ cursor, int* __restrict__ esrc, int E)
{
    int e = blockIdx.x * 256 + threadIdx.x;
    if (e >= E) return;
    int pos = atomicAdd(&cursor[dst[e]], 1);
    esrc[pos] = src[e];
}

// ---------------- GEMM: acc = A16[r] @ Wp ----------------
// A16 rows stride 152 halves; Wp [146][160] fp32. 320 thr: 8 rowgroups x 40 colgroups.
// Epilogue: if C32: C32 = acc+bias (fp32, the residual state h) AND C16 = fp16((acc+bias)*rowscale) stride c16s.
//           else:   C16 = fp16(acc) stride c16s (layer hW).
__global__ __launch_bounds__(320) void gemm146(
    const __half* __restrict__ A16, const float* __restrict__ Wp,
    __half2* __restrict__ C16, float* __restrict__ C32, int nrows,
    const float* __restrict__ rowscale, const float* __restrict__ bias, int c16s)
{
    __shared__ __half As[64 * AS];
    int tid = threadIdx.x;
    int row0 = blockIdx.x * 64;

    {
        const uint4* A4 = reinterpret_cast<const uint4*>(A16);
        uint4* S4 = reinterpret_cast<uint4*>(As);
        for (int i = tid; i < 64 * (AS / 8); i += 320) {
            int r = i / (AS / 8), ch = i % (AS / 8);
            int gr = row0 + r;
            if (gr > nrows - 1) gr = nrows - 1;
            S4[i] = A4[(size_t)gr * (AS / 8) + ch];
        }
    }
    __syncthreads();

    int cg = tid % 40, rg = tid / 40;
    const float4* W4 = reinterpret_cast<const float4*>(Wp);
    float acc[8][4] = {};
    for (int k = 0; k < D; k += 2) {
        float4 w0 = W4[k * 40 + cg];
        float4 w1 = W4[(k + 1) * 40 + cg];
#pragma unroll
        for (int i = 0; i < 8; ++i) {
            __half2 h01 = *reinterpret_cast<const __half2*>(&As[(rg * 8 + i) * AS + k]);
            float2 a = __half22float2(h01);
            acc[i][0] = fmaf(a.x, w0.x, acc[i][0]);
            acc[i][1] = fmaf(a.x, w0.y, acc[i][1]);
            acc[i][2] = fmaf(a.x, w0.z, acc[i][2]);
            acc[i][3] = fmaf(a.x, w0.w, acc[i][3]);
            acc[i][0] = fmaf(a.y, w1.x, acc[i][0]);
            acc[i][1] = fmaf(a.y, w1.y, acc[i][1]);
            acc[i][2] = fmaf(a.y, w1.z, acc[i][2]);
            acc[i][3] = fmaf(a.y, w1.w, acc[i][3]);
        }
    }

    int c = cg * 4;
    if (c >= D) return;
    bool second = (c + 2 < D);
#pragma unroll
    for (int i = 0; i < 8; ++i) {
        int r = row0 + rg * 8 + i;
        if (r >= nrows) continue;
        if (C32) {
            float v0 = acc[i][0] + bias[c], v1 = acc[i][1] + bias[c + 1];
            float2 t; t.x = v0; t.y = v1;
            *reinterpret_cast<float2*>(&C32[(size_t)r * D + c]) = t;
            float s = rowscale[r];
            C16[(size_t)r * c16s + (c >> 1)] = __floats2half2_rn(v0 * s, v1 * s);
            if (second) {
                float v2 = acc[i][2] + bias[c + 2], v3 = acc[i][3] + bias[c + 3];
                float2 t2; t2.x = v2; t2.y = v3;
                *reinterpret_cast<float2*>(&C32[(size_t)r * D + c + 2]) = t2;
                C16[(size_t)r * c16s + (c >> 1) + 1] = __floats2half2_rn(v2 * s, v3 * s);
            }
        } else {
            C16[(size_t)r * c16s + (c >> 1)] = __floats2half2_rn(acc[i][0], acc[i][1]);
            if (second)
                C16[(size_t)r * c16s + (c >> 1) + 1] = __floats2half2_rn(acc[i][2], acc[i][3]);
        }
    }
}

// ---------------- CSR gather-sum (fp16 payload) + p1 epilogue + BN stats ----------------
// lane owns half2 cols {lane, 64+lane(if lane<9)} i.e. scalar cols {2l,2l+1, 128+2l,129+2l}
__global__ __launch_bounds__(256) void agg_k(
    const __half2* __restrict__ hW2, const int* __restrict__ esrc,
    const int* __restrict__ rowptr, const float* __restrict__ nd,
    const float* __restrict__ sn, const float* __restrict__ bias,
    __half2* __restrict__ hpre2, float* __restrict__ stats, int N)
{
    __shared__ float rs[4][D];
    __shared__ float rq[4][D];
    int lane = threadIdx.x & 63, wave = threadIdx.x >> 6;
    int per = (N + gridDim.x - 1) / gridDim.x;
    int n0 = blockIdx.x * per;
    int n1 = min(N, n0 + per);
    int wper = (per + 3) >> 2;
    int w0 = min(n1, n0 + wave * wper);
    int w1 = min(n1, w0 + wper);

    bool v1 = lane < 9;
    int j0 = lane, j1 = 64 + lane;
    int c0 = 2 * lane, c1 = 128 + 2 * lane;
    int c1m = v1 ? c1 : 0;
    float b00 = bias[c0], b01 = bias[c0 + 1];
    float b10 = bias[c1m], b11 = bias[c1m + 1];
    float s00 = 0, s01 = 0, s10 = 0, s11 = 0, q00 = 0, q01 = 0, q10 = 0, q11 = 0;

    for (int n = w0; n < w1; ++n) {
        int e = rowptr[n], ee = rowptr[n + 1];
        float a00 = 0, a01 = 0, a10 = 0, a11 = 0;
        float d00 = 0, d01 = 0, d10 = 0, d11 = 0;
        for (; e + 1 < ee; e += 2) {
            const __half2* ra = hW2 + (size_t)esrc[e] * (D / 2);
            const __half2* rb = hW2 + (size_t)esrc[e + 1] * (D / 2);
            float2 fa = __half22float2(ra[j0]); a00 += fa.x; a01 += fa.y;
            float2 fb = __half22float2(rb[j0]); d00 += fb.x; d01 += fb.y;
            if (v1) {
                float2 ga = __half22float2(ra[j1]); a10 += ga.x; a11 += ga.y;
                float2 gb = __half22float2(rb[j1]); d10 += gb.x; d11 += gb.y;
            }
        }
        if (e < ee) {
            const __half2* ra = hW2 + (size_t)esrc[e] * (D / 2);
            float2 fa = __half22float2(ra[j0]); a00 += fa.x; a01 += fa.y;
            if (v1) { float2 ga = __half22float2(ra[j1]); a10 += ga.x; a11 += ga.y; }
        }
        a00 += d00; a01 += d01; a10 += d10; a11 += d11;
        float ndv = nd[n], snv = sn[n];
        float h00 = (a00 * ndv + b00) * snv;
        float h01 = (a01 * ndv + b01) * snv;
        hpre2[(size_t)n * (D / 2) + j0] = __floats2half2_rn(h00, h01);
        s00 += h00; q00 = fmaf(h00, h00, q00);
        s01 += h01; q01 = fmaf(h01, h01, q01);
        if (v1) {
            float h10 = (a10 * ndv + b10) * snv;
            float h11 = (a11 * ndv + b11) * snv;
            hpre2[(size_t)n * (D / 2) + j1] = __floats2half2_rn(h10, h11);
            s10 += h10; q10 = fmaf(h10, h10, q10);
            s11 += h11; q11 = fmaf(h11, h11, q11);
        }
    }
    rs[wave][c0] = s00; rs[wave][c0 + 1] = s01;
    rq[wave][c0] = q00; rq[wave][c0 + 1] = q01;
    if (v1) {
        rs[wave][c1] = s10; rs[wave][c1 + 1] = s11;
        rq[wave][c1] = q10; rq[wave][c1 + 1] = q11;
    }
    __syncthreads();
    for (int cc = threadIdx.x; cc < D; cc += 256) {
        atomicAdd(&stats[cc], rs[0][cc] + rs[1][cc] + rs[2][cc] + rs[3][cc]);
        atomicAdd(&stats[D + cc], rq[0][cc] + rq[1][cc] + rq[2][cc] + rq[3][cc]);
    }
}

__global__ void bnfin_k(float* __restrict__ stats, int N)
{
    int c = threadIdx.x;
    if (c >= D) return;
    float mean = stats[c] / (float)N;
    float var = stats[D + c] / (float)N - mean * mean;
    if (var < 0.0f) var = 0.0f;
    stats[2 * D + c] = mean;
    stats[3 * D + c] = rsqrtf(var + BN_EPS);
}

// ---------------- h += relu(bn(hpre)); hs16 = h*nsrc; hg pooling ----------------
__global__ __launch_bounds__(256) void p2hg_k(
    float* __restrict__ h, const __half2* __restrict__ hpre2,
    const float* __restrict__ stats, const float* __restrict__ gamma,
    const float* __restrict__ beta, const float* __restrict__ sn,
    const float* __restrict__ nsrc, const int* __restrict__ gid,
    __half2* __restrict__ hs2, float* __restrict__ hg, int N)
{
    int lane = threadIdx.x & 63, wave = threadIdx.x >> 6;
    int per = (N + gridDim.x - 1) / gridDim.x;
    int n0 = blockIdx.x * per;
    int n1 = min(N, n0 + per);
    int wper = (per + 3) >> 2;
    int w0 = min(n1, n0 + wave * wper);
    int w1 = min(n1, w0 + wper);
    if (w0 >= w1) return;

    bool v1 = lane < 9;
    int j0 = lane, j1 = 64 + lane;
    int c0 = 2 * lane, c1 = 128 + 2 * lane;
    int c1m = v1 ? c1 : 0;
    float m00 = stats[2 * D + c0], m01 = stats[2 * D + c0 + 1];
    float r00 = stats[3 * D + c0], r01 = stats[3 * D + c0 + 1];
    float g00 = gamma[c0], g01 = gamma[c0 + 1], t00 = beta[c0], t01 = beta[c0 + 1];
    float m10 = stats[2 * D + c1m], m11 = stats[2 * D + c1m + 1];
    float r10 = stats[3 * D + c1m], r11 = stats[3 * D + c1m + 1];
    float g10 = gamma[c1m], g11 = gamma[c1m + 1], t10 = beta[c1m], t11 = beta[c1m + 1];

    int g = gid[w0];
    float a00 = 0, a01 = 0, a10 = 0, a11 = 0;
    for (int n = w0; n < w1; ++n) {
        int gr = gid[n];
        if (gr != g) {
            atomicAdd(&hg[(size_t)g * D + c0], a00);
            atomicAdd(&hg[(size_t)g * D + c0 + 1], a01);
            if (v1) {
                atomicAdd(&hg[(size_t)g * D + c1], a10);
                atomicAdd(&hg[(size_t)g * D + c1 + 1], a11);
            }
            a00 = a01 = a10 = a11 = 0;
            g = gr;
        }
        float ns = nsrc[n];
        float w2 = sn[n]; w2 *= w2;
        float2 hv = *reinterpret_cast<float2*>(&h[(size_t)n * D + c0]);
        float2 p0 = __half22float2(hpre2[(size_t)n * (D / 2) + j0]);
        float x0 = hv.x + fmaxf((p0.x - m00) * r00 * g00 + t00, 0.0f);
        float x1 = hv.y + fmaxf((p0.y - m01) * r01 * g01 + t01, 0.0f);
        hv.x = x0; hv.y = x1;
        *reinterpret_cast<float2*>(&h[(size_t)n * D + c0]) = hv;
        hs2[(size_t)n * (AS / 2) + j0] = __floats2half2_rn(x0 * ns, x1 * ns);
        a00 = fmaf(x0, w2, a00);
        a01 = fmaf(x1, w2, a01);
        if (v1) {
            float2 hv1 = *reinterpret_cast<float2*>(&h[(size_t)n * D + c1]);
            float2 p1 = __half22float2(hpre2[(size_t)n * (D / 2) + j1]);
            float x2 = hv1.x + fmaxf((p1.x - m10) * r10 * g10 + t10, 0.0f);
            float x3 = hv1.y + fmaxf((p1.y - m11) * r11 * g11 + t11, 0.0f);
            hv1.x = x2; hv1.y = x3;
            *reinterpret_cast<float2*>(&h[(size_t)n * D + c1]) = hv1;
            hs2[(size_t)n * (AS / 2) + j1] = __floats2half2_rn(x2 * ns, x3 * ns);
            a10 = fmaf(x2, w2, a10);
            a11 = fmaf(x3, w2, a11);
        }
    }
    atomicAdd(&hg[(size_t)g * D + c0], a00);
    atomicAdd(&hg[(size_t)g * D + c0 + 1], a01);
    if (v1) {
        atomicAdd(&hg[(size_t)g * D + c1], a10);
        atomicAdd(&hg[(size_t)g * D + c1 + 1], a11);
    }
}

// ---------------- small dense layer (readout) ----------------
__global__ void sgemm_k(const float* __restrict__ A, const float* __restrict__ W,
                        const float* __restrict__ b, float* __restrict__ Cc,
                        int M, int K, int Nc, int dorelu)
{
    int idx = blockIdx.x * 256 + threadIdx.x;
    if (idx >= M * Nc) return;
    int m = idx / Nc, n = idx % Nc;
    float s = b[n];
    for (int k = 0; k < K; ++k) s = fmaf(A[(size_t)m * K + k], W[(size_t)k * Nc + n], s);
    Cc[idx] = dorelu ? fmaxf(s, 0.0f) : s;
}

extern "C" void kernel_launch(void* const* d_in, const int* in_sizes, int n_in,
                              void* d_out, int out_size, void* d_ws, size_t ws_size,
                              hipStream_t stream)
{
    const float* nodes  = (const float*)d_in[0];
    const float* snorm  = (const float*)d_in[1];
    const float* Wemb   = (const float*)d_in[2];
    const float* bemb   = (const float*)d_in[3];
    const float* Ws     = (const float*)d_in[4];
    const float* bs     = (const float*)d_in[5];
    const float* gammas = (const float*)d_in[6];
    const float* betas  = (const float*)d_in[7];
    const float* Wr0    = (const float*)d_in[8];
    const float* br0    = (const float*)d_in[9];
    const float* Wr1    = (const float*)d_in[10];
    const float* br1    = (const float*)d_in[11];
    const float* Wr2    = (const float*)d_in[12];
    const float* br2    = (const float*)d_in[13];
    const int*   src    = (const int*)d_in[14];
    const int*   dst    = (const int*)d_in[15];
    const int*   gid    = (const int*)d_in[16];

    int N = in_sizes[0] / D;
    int E = in_sizes[14];
    int nb = (N + 255) / 256;

    float* ws = (float*)d_ws;
    size_t off = 0;
    float* Wp    = ws + off; off += (size_t)5 * D * DP;
    float* nsrc  = ws + off; off += N;
    float* ndst  = ws + off; off += N;
    float* h     = ws + off; off += (size_t)N * D;
    float* stats = ws + off; off += 4 * 4 * D;           // 4 layer slabs
    float* hg    = ws + off; off += (size_t)NG * D;      // contiguous with stats: one memset
    float* z1    = ws + off; off += (size_t)NG * 73;
    float* z2    = ws + off; off += (size_t)NG * 36;
    int* cnt_out = (int*)(ws + off); off += N;
    int* cnt_in  = (int*)(ws + off); off += N;
    int* rowptr  = (int*)(ws + off); off += N + 4;
    int* cursor  = (int*)(ws + off); off += N;
    int* esrc    = (int*)(ws + off); off += E;
    int* bsum    = (int*)(ws + off); off += 256;
    int* boff    = (int*)(ws + off); off += 256;
    off = (off + 7) & ~(size_t)7;                        // 16B-align the half region
    __half* hs16    = (__half*)(ws + off); off += (size_t)N * AS / 2;
    __half* nodes16 = (__half*)(ws + off);               // aliases hW16 region (disjoint lifetime)
    __half* hW16    = (__half*)(ws + off); off += (size_t)N * AS / 2;  // sized for the larger alias
    __half* hpre16  = (__half*)(ws + off); off += (size_t)N * D / 2;

    // setup
    hipMemsetAsync(cnt_out, 0, 2 * (size_t)N * sizeof(int), stream);
    hipMemsetAsync(stats, 0, (16 * D + (size_t)NG * D) * sizeof(float), stream);
    padw_k<<<(5 * D * DP + 255) / 256, 256, 0, stream>>>(Wemb, Ws, Wp);
    cvtnodes_k<<<(N * (AS / 2) + 255) / 256, 256, 0, stream>>>(nodes, (__half2*)nodes16, N);
    deg_k<<<(E + 255) / 256, 256, 0, stream>>>(src, dst, cnt_out, cnt_in, E);
    rsq_k<<<(N + 255) / 256, 256, 0, stream>>>(cnt_out, cnt_in, nsrc, ndst, N);
    pscan1_k<<<nb, 256, 0, stream>>>(cnt_in, bsum, N);
    pscan2_k<<<1, 256, 0, stream>>>(bsum, boff, nb);
    pscan3_k<<<nb, 256, 0, stream>>>(cnt_in, boff, rowptr, cursor, N, E);
    csrfill_k<<<(E + 255) / 256, 256, 0, stream>>>(src, dst, cursor, esrc, E);

    int gblk = (N + 63) / 64;
    // embedding: h = nodes@Wemb + b (fp32), hs16 = fp16(h*nsrc) stride 152
    gemm146<<<gblk, 320, 0, stream>>>(nodes16, Wp, (__half2*)hs16, h, N, nsrc, bemb, AS / 2);

    for (int l = 0; l < 4; ++l) {
        float* st = stats + (size_t)l * 4 * D;
        gemm146<<<gblk, 320, 0, stream>>>(hs16, Wp + (size_t)(l + 1) * D * DP,
                                          (__half2*)hW16, nullptr, N, nullptr, nullptr, D / 2);
        agg_k<<<1024, 256, 0, stream>>>((const __half2*)hW16, esrc, rowptr, ndst, snorm,
                                        bs + (size_t)l * D, (__half2*)hpre16, st, N);
        bnfin_k<<<1, 256, 0, stream>>>(st, N);
        p2hg_k<<<512, 256, 0, stream>>>(h, (const __half2*)hpre16, st,
                                        gammas + (size_t)l * D, betas + (size_t)l * D,
                                        snorm, nsrc, gid, (__half2*)hs16, hg, N);
    }

    // readout MLP: 146 -> 73 -> 36 -> 10
    sgemm_k<<<(NG * 73 + 255) / 256, 256, 0, stream>>>(hg, Wr0, br0, z1, NG, D, 73, 1);
    sgemm_k<<<(NG * 36 + 255) / 256, 256, 0, stream>>>(z1, Wr1, br1, z2, NG, 73, 36, 1);
    sgemm_k<<<(NG * 10 + 255) / 256, 256, 0, stream>>>(z2, Wr2, br2, (float*)d_out, NG, 36, 10, 0);
}